// Round 7
// baseline (192.428 us; speedup 1.0000x reference)
//
#include <hip/hip_runtime.h>
#include <hip/hip_bf16.h>

constexpr int D        = 100;
constexpr int K        = 20;
constexpr int N_USER   = 50000;
constexpr int N_ENTITY = 60000;
constexpr int N_NEWS   = 20000;
constexpr int NNZ      = 500000;
constexpr int CAP      = 32;     // bucket capacity per user (avg degree = 10)
constexpr int N_NODE   = N_NEWS + N_ENTITY;
constexpr int HS       = 64;     // half-row stride (elems) = 128 B = 1 line

// ---- bf16 helpers ---------------------------------------------------------
static __device__ __forceinline__ unsigned short f2b(float x) {
    union { float f; unsigned int u; } c; c.f = x;
    unsigned int u = c.u;
    return (unsigned short)((u + 0x7FFFu + ((u >> 16) & 1u)) >> 16);
}
static __device__ __forceinline__ float blo(unsigned int t) {
    union { unsigned int u; float f; } c; c.u = t << 16; return c.f;
}
static __device__ __forceinline__ float bhi(unsigned int t) {
    union { unsigned int u; float f; } c; c.u = t & 0xFFFF0000u; return c.f;
}

// ---------------------------------------------------------------------------
// prep: f32 -> bf16 column-split tables (lo = elems 0..63, hi = 64..99 + pad)
// + zero counts + zero overflow-list counter.
// One thread per ushort4 slot; 32 slots per row (16 lo + 16 hi).
// ---------------------------------------------------------------------------
constexpr int CVT_T = N_ENTITY * 32;

__global__ __launch_bounds__(256) void prep_kernel(
    const float* __restrict__ ent, const float* __restrict__ all,
    ushort4* __restrict__ entLo4, ushort4* __restrict__ entHi4,
    ushort4* __restrict__ allLo4, ushort4* __restrict__ allHi4,
    int* __restrict__ counts, int* __restrict__ listcnt)
{
    int i = (int)(blockIdx.x * blockDim.x + threadIdx.x);
    if (i < 2 * CVT_T) {
        bool isEnt = i < CVT_T;
        const float* src = isEnt ? ent : all;
        int j    = isEnt ? i : i - CVT_T;
        int row  = j >> 5;
        int slot = j & 31;
        int e = (slot < 16) ? slot * 4 : 64 + (slot - 16) * 4;
        ushort4 o = make_ushort4(0, 0, 0, 0);
        if (e < D) {   // e in {0..96 step 4}; e=96 covers 96..99
            const float* sp = src + (size_t)row * D + e;
            float v0 = __builtin_nontemporal_load(sp + 0);
            float v1 = __builtin_nontemporal_load(sp + 1);
            float v2 = __builtin_nontemporal_load(sp + 2);
            float v3 = __builtin_nontemporal_load(sp + 3);
            o.x = f2b(v0); o.y = f2b(v1); o.z = f2b(v2); o.w = f2b(v3);
        }
        ushort4* dst = isEnt ? ((slot < 16) ? entLo4 : entHi4)
                             : ((slot < 16) ? allLo4 : allHi4);
        dst[(size_t)row * 16 + (slot & 15)] = o;
    } else {
        int j = i - 2 * CVT_T;
        if (j < N_USER) counts[j] = 0;
        else if (j == N_USER) *listcnt = 0;
    }
}

// ---------------------------------------------------------------------------
// Bucket build: counts + interleaved (col,val) int2 fill + overflow list
// ---------------------------------------------------------------------------
__global__ __launch_bounds__(256) void hist_fill_kernel(
    const int* __restrict__ rows, const int* __restrict__ cols,
    const float* __restrict__ vals,
    int* __restrict__ counts, int2* __restrict__ bpair,
    int* __restrict__ list, int* __restrict__ listcnt, int nnz)
{
    int j = (int)(blockIdx.x * blockDim.x + threadIdx.x);
    if (j >= nnz) return;
    int r   = __builtin_nontemporal_load(rows + j);
    int pos = atomicAdd(&counts[r], 1);
    if (pos < CAP) {
        int   c = __builtin_nontemporal_load(cols + j);
        float v = __builtin_nontemporal_load(vals + j);
        bpair[(size_t)r * CAP + pos] = make_int2(c, __float_as_int(v));
    } else {
        int s = atomicAdd(listcnt, 1);   // s < nnz always
        list[s] = j;
    }
}

// ---------------------------------------------------------------------------
// Neighbor-sum aggregation (softmax over size-1 axis == 1.0), column-split
// two-phase sweep. Dual-row waves: lanes 0-31 -> row 2p, lanes 32-63 -> 2p+1.
// Phase 0 gathers lo half-table (elems 0..63), phase 1 hi (64..99).
// Writes f32 node + bf16 nodeLo/nodeHi shadows.
// ---------------------------------------------------------------------------
__global__ __launch_bounds__(256) void sumagg_kernel(
    const unsigned short* __restrict__ tabLo,
    const unsigned short* __restrict__ tabHi,
    const int*   __restrict__ idx_mat,   // n x K
    const float* __restrict__ base,      // f32 residual rows
    float*       __restrict__ node,      // f32 out rows (pre-offset)
    unsigned short* __restrict__ nodeLo, // bf16 lo shadow (pre-offset)
    unsigned short* __restrict__ nodeHi, // bf16 hi shadow (pre-offset)
    int n)
{
    int w    = threadIdx.x >> 6;
    int lane = threadIdx.x & 63;
    int li   = lane & 31;
    int sub  = lane >> 5;
    int slot   = (int)blockIdx.x * 4 + w;
    int nslots = (int)gridDim.x * 4;
    int npair  = n >> 1;

    for (int ph = 0; ph < 2; ++ph) {
        const unsigned short* tab = ph ? tabHi : tabLo;
        for (int pair = slot; pair < npair; pair += nslots) {
            int row = pair * 2 + sub;
            int idxv = (li < K)
                ? __builtin_nontemporal_load(idx_mat + (size_t)row * K + li) : 0;
            unsigned int t[K];
            #pragma unroll
            for (int k = 0; k < K; ++k) {
                int col = __shfl(idxv, sub * 32 + k);
                t[k] = *(const unsigned int*)(tab + (size_t)col * HS + li * 2);
            }
            float a0 = 0.f, a1 = 0.f;
            #pragma unroll
            for (int k = 0; k < K; ++k) { a0 += blo(t[k]); a1 += bhi(t[k]); }

            if (ph == 0) {
                const float* bp = base + (size_t)row * D + li * 2;
                float b0 = __builtin_nontemporal_load(bp);
                float b1 = __builtin_nontemporal_load(bp + 1);
                float o0 = a0 + b0, o1 = a1 + b1;
                float* np = node + (size_t)row * D + li * 2;
                __builtin_nontemporal_store(o0, np);
                __builtin_nontemporal_store(o1, np + 1);
                unsigned int packed = (unsigned int)f2b(o0)
                                    | ((unsigned int)f2b(o1) << 16);
                *(unsigned int*)(nodeLo + (size_t)row * HS + li * 2) = packed;
            } else {
                unsigned int packed = 0;
                if (li < 18) {   // elems 64..99 = 18 lanes x 2
                    int e = 64 + li * 2;
                    const float* bp = base + (size_t)row * D + e;
                    float b0 = __builtin_nontemporal_load(bp);
                    float b1 = __builtin_nontemporal_load(bp + 1);
                    float o0 = a0 + b0, o1 = a1 + b1;
                    float* np = node + (size_t)row * D + e;
                    __builtin_nontemporal_store(o0, np);
                    __builtin_nontemporal_store(o1, np + 1);
                    packed = (unsigned int)f2b(o0)
                           | ((unsigned int)f2b(o1) << 16);
                }
                *(unsigned int*)(nodeHi + (size_t)row * HS + li * 2) = packed;
            }
        }
    }
}

// ---------------------------------------------------------------------------
// Per-user aggregate, column-split two-phase sweep, dual-user waves.
//   user[u,:] = user_emb[u,:] + sum vals*node[cols,:]
// ---------------------------------------------------------------------------
__global__ __launch_bounds__(256) void user_agg_kernel(
    const int* __restrict__ counts, const int2* __restrict__ bpair,
    const unsigned short* __restrict__ nodeLo,
    const unsigned short* __restrict__ nodeHi,
    const float* __restrict__ user_emb, float* __restrict__ user)
{
    int w    = threadIdx.x >> 6;
    int lane = threadIdx.x & 63;
    int li   = lane & 31;
    int sub  = lane >> 5;
    int slot   = (int)blockIdx.x * 4 + w;
    int nslots = (int)gridDim.x * 4;
    int npair  = N_USER / 2;

    for (int ph = 0; ph < 2; ++ph) {
        const unsigned short* tab = ph ? nodeHi : nodeLo;
        for (int pair = slot; pair < npair; pair += nslots) {
            int u = pair * 2 + sub;
            int c = counts[u];
            if (c > CAP) c = CAP;
            int cmax = max(c, __shfl(c, lane ^ 32));

            int colv = 0; float valv = 0.f;
            if (li < c) {
                int2 bp = bpair[(size_t)u * CAP + li];
                colv = bp.x; valv = __int_as_float(bp.y);
            }
            int clamp = (c > 0) ? (c - 1) : 0;

            float a0 = 0.f, a1 = 0.f;
            for (int e0 = 0; e0 < cmax; e0 += 8) {
                unsigned int t[8]; float v[8];
                #pragma unroll
                for (int e = 0; e < 8; ++e) {
                    int ee = e0 + e;
                    int es = (ee < clamp) ? ee : clamp;  // dup loads -> L1 hits
                    int   col = __shfl(colv, sub * 32 + es);
                    float vv  = __shfl(valv, sub * 32 + es);
                    v[e] = (ee < c) ? vv : 0.f;
                    t[e] = *(const unsigned int*)(tab + (size_t)col * HS + li * 2);
                }
                #pragma unroll
                for (int e = 0; e < 8; ++e) {
                    a0 += v[e] * blo(t[e]); a1 += v[e] * bhi(t[e]);
                }
            }
            if (ph == 0) {
                const float* up = user_emb + (size_t)u * D + li * 2;
                float u0 = __builtin_nontemporal_load(up);
                float u1 = __builtin_nontemporal_load(up + 1);
                float* op = user + (size_t)u * D + li * 2;
                __builtin_nontemporal_store(a0 + u0, op);
                __builtin_nontemporal_store(a1 + u1, op + 1);
            } else if (li < 18) {
                int e = 64 + li * 2;
                const float* up = user_emb + (size_t)u * D + e;
                float u0 = __builtin_nontemporal_load(up);
                float u1 = __builtin_nontemporal_load(up + 1);
                float* op = user + (size_t)u * D + e;
                __builtin_nontemporal_store(a0 + u0, op);
                __builtin_nontemporal_store(a1 + u1, op + 1);
            }
        }
    }
}

// ---------------------------------------------------------------------------
// Overflow drain: entries hist pushed past CAP (none expected for this
// input). Wave per list entry; f32 node; atomic adds. Runs AFTER user_agg.
// ---------------------------------------------------------------------------
__global__ __launch_bounds__(256) void drain_kernel(
    const int* __restrict__ list, const int* __restrict__ listcnt,
    const int* __restrict__ rows, const int* __restrict__ cols,
    const float* __restrict__ vals, const float* __restrict__ node,
    float* __restrict__ user)
{
    int nw   = (int)((gridDim.x * blockDim.x) >> 6);
    int wid  = (int)((blockIdx.x * blockDim.x + threadIdx.x) >> 6);
    int lane = threadIdx.x & 63;
    int cnt  = *listcnt;
    if (cnt > NNZ) cnt = NNZ;
    for (int s = wid; s < cnt; s += nw) {
        int j = list[s];
        int   r = rows[j];
        int   c = cols[j];
        float v = vals[j];
        const float* src = node + (size_t)c * D;
        float*       dst = user + (size_t)r * D;
        unsafeAtomicAdd(&dst[lane], v * src[lane]);
        int l2 = lane + 64;
        if (l2 < D) unsafeAtomicAdd(&dst[l2], v * src[l2]);
    }
}

// ---------------------------------------------------------------------------
// Fallback tiers (f32; only if workspace too small — never hit in practice)
// ---------------------------------------------------------------------------
__global__ __launch_bounds__(256) void zero2_kernel(
    int* __restrict__ counts, int* __restrict__ listcnt, int n)
{
    int i = (int)(blockIdx.x * blockDim.x + threadIdx.x);
    if (i < n) counts[i] = 0;
    else if (i == n) *listcnt = 0;
}

__global__ __launch_bounds__(256) void sumagg_f32_kernel(
    const float* __restrict__ table, const int* __restrict__ idx_mat,
    const float* __restrict__ base, float* __restrict__ out, int n)
{
    int wave = (int)((blockIdx.x * blockDim.x + threadIdx.x) >> 6);
    int lane = threadIdx.x & 63;
    if (wave >= n) return;
    int idxv = (lane < K) ? idx_mat[(size_t)wave * K + lane] : 0;
    float acc0 = 0.f, acc1 = 0.f;
    int l2 = lane + 64;
    #pragma unroll
    for (int k = 0; k < K; ++k) {
        int ei = __shfl(idxv, k);
        const float* r = table + (size_t)ei * D;
        acc0 += r[lane];
        if (l2 < D) acc1 += r[l2];
    }
    const float* b = base + (size_t)wave * D;
    float*       o = out  + (size_t)wave * D;
    o[lane] = acc0 + b[lane];
    if (l2 < D) o[l2] = acc1 + b[l2];
}

__global__ __launch_bounds__(256) void user_agg_f32_kernel(
    const int* __restrict__ counts, const int2* __restrict__ bpair,
    const float* __restrict__ node,
    const float* __restrict__ user_emb, float* __restrict__ user)
{
    int u    = (int)((blockIdx.x * blockDim.x + threadIdx.x) >> 6);
    int lane = threadIdx.x & 63;
    if (u >= N_USER) return;
    int c = counts[u];
    if (c > CAP) c = CAP;
    int colv = 0; float valv = 0.f;
    if (lane < c) {
        int2 bp = bpair[(size_t)u * CAP + lane];
        colv = bp.x; valv = __int_as_float(bp.y);
    }
    float a0 = 0.f, a1 = 0.f;
    int l2 = lane + 64;
    for (int e = 0; e < c; ++e) {
        int   col = __shfl(colv, e);
        float v   = __shfl(valv, e);
        const float* r = node + (size_t)col * D;
        a0 += v * r[lane];
        if (l2 < D) a1 += v * r[l2];
    }
    const float* ue = user_emb + (size_t)u * D;
    float*       o  = user     + (size_t)u * D;
    o[lane] = a0 + ue[lane];
    if (l2 < D) o[l2] = a1 + ue[l2];
}

__global__ __launch_bounds__(256) void copy_kernel(
    const float4* __restrict__ src, float4* __restrict__ dst, int n4)
{
    int i = (int)(blockIdx.x * blockDim.x + threadIdx.x);
    if (i < n4) dst[i] = src[i];
}

__global__ __launch_bounds__(256) void scatter_kernel(
    const float* __restrict__ vals, const int* __restrict__ rows,
    const int* __restrict__ cols, const float* __restrict__ node,
    float* __restrict__ user, int nnz)
{
    int j    = (int)((blockIdx.x * blockDim.x + threadIdx.x) >> 6);
    int lane = threadIdx.x & 63;
    if (j >= nnz) return;
    int   r = rows[j];
    int   c = cols[j];
    float v = vals[j];
    const float* src = node + (size_t)c * D;
    float*       dst = user + (size_t)r * D;
    unsafeAtomicAdd(&dst[lane], v * src[lane]);
    int l2 = lane + 64;
    if (l2 < D) unsafeAtomicAdd(&dst[l2], v * src[l2]);
}

// ---------------------------------------------------------------------------
extern "C" void kernel_launch(void* const* d_in, const int* in_sizes, int n_in,
                              void* d_out, int out_size, void* d_ws, size_t ws_size,
                              hipStream_t stream)
{
    const float* user_emb = (const float*)d_in[0];
    const float* all_emb  = (const float*)d_in[1];
    const float* ent_emb  = (const float*)d_in[2];
    // d_in[3..7]: relation_emb, W_news, b_news, W_ent, b_ent — dead inputs
    // (softmax over a size-1 axis is identically 1.0 in the reference).
    const float* vals     = (const float*)d_in[8];
    const int*   news_ent = (const int*)d_in[9];
    const int*   ngh_ent  = (const int*)d_in[11];
    const int*   irows    = (const int*)d_in[13];
    const int*   icols    = (const int*)d_in[14];

    float* node = (float*)d_out;                         // 80000 x 100
    float* user = (float*)d_out + (size_t)N_NODE * D;    // 50000 x 100

    // workspace layout (tier A)
    int*   counts  = (int*)d_ws;                              // N_USER
    int*   list    = counts + N_USER;                         // NNZ
    int*   listcnt = list + NNZ;                              // 1 (+63 pad)
    int2*  bpair   = (int2*)(listcnt + 64);                   // N_USER*CAP int2
    unsigned short* entLo  = (unsigned short*)(bpair + (size_t)N_USER * CAP);
    unsigned short* entHi  = entLo  + (size_t)N_ENTITY * HS;
    unsigned short* allLo  = entHi  + (size_t)N_ENTITY * HS;
    unsigned short* allHi  = allLo  + (size_t)N_ENTITY * HS;
    unsigned short* nodeLo = allHi  + (size_t)N_ENTITY * HS;
    unsigned short* nodeHi = nodeLo + (size_t)N_NODE * HS;

    size_t need_bucket = ((size_t)N_USER + NNZ + 64) * 4ull
                       + (size_t)N_USER * CAP * 8ull;
    size_t need_full   = need_bucket
                       + (4ull * N_ENTITY * HS + 2ull * N_NODE * HS) * 2ull;

    if (ws_size >= need_full) {
        // ---- tier A: column-split bf16 tables, two-phase persistent sweeps
        int prep_n = 2 * CVT_T + N_USER + 1;
        prep_kernel<<<(prep_n + 255) / 256, 256, 0, stream>>>(
            ent_emb, all_emb, (ushort4*)entLo, (ushort4*)entHi,
            (ushort4*)allLo, (ushort4*)allHi, counts, listcnt);
        hist_fill_kernel<<<(NNZ + 255) / 256, 256, 0, stream>>>(
            irows, icols, vals, counts, bpair, list, listcnt, NNZ);
        // news phase: gathers bf16(entity_emb)
        sumagg_kernel<<<2048, 256, 0, stream>>>(
            entLo, entHi, news_ent, all_emb, node, nodeLo, nodeHi, N_NEWS);
        // entity phase: gathers bf16(all_embedding)
        sumagg_kernel<<<2048, 256, 0, stream>>>(
            allLo, allHi, ngh_ent, all_emb,
            node + (size_t)N_NEWS * D,
            nodeLo + (size_t)N_NEWS * HS, nodeHi + (size_t)N_NEWS * HS,
            N_ENTITY);
        user_agg_kernel<<<2048, 256, 0, stream>>>(
            counts, bpair, nodeLo, nodeHi, user_emb, user);
        drain_kernel<<<64, 256, 0, stream>>>(
            list, listcnt, irows, icols, vals, node, user);
    } else if (ws_size >= need_bucket) {
        // ---- tier B: f32 bucket-gather ----
        sumagg_f32_kernel<<<(N_NEWS + 3) / 4, 256, 0, stream>>>(
            ent_emb, news_ent, all_emb, node, N_NEWS);
        sumagg_f32_kernel<<<(N_ENTITY + 3) / 4, 256, 0, stream>>>(
            all_emb, ngh_ent, all_emb, node + (size_t)N_NEWS * D, N_ENTITY);
        zero2_kernel<<<(N_USER + 256) / 256, 256, 0, stream>>>(
            counts, listcnt, N_USER);
        hist_fill_kernel<<<(NNZ + 255) / 256, 256, 0, stream>>>(
            irows, icols, vals, counts, bpair, list, listcnt, NNZ);
        user_agg_f32_kernel<<<(N_USER + 3) / 4, 256, 0, stream>>>(
            counts, bpair, node, user_emb, user);
        drain_kernel<<<64, 256, 0, stream>>>(
            list, listcnt, irows, icols, vals, node, user);
    } else {
        // ---- tier C: atomic scatter ----
        sumagg_f32_kernel<<<(N_NEWS + 3) / 4, 256, 0, stream>>>(
            ent_emb, news_ent, all_emb, node, N_NEWS);
        sumagg_f32_kernel<<<(N_ENTITY + 3) / 4, 256, 0, stream>>>(
            all_emb, ngh_ent, all_emb, node + (size_t)N_NEWS * D, N_ENTITY);
        int n4 = N_USER * D / 4;
        copy_kernel<<<(n4 + 255) / 256, 256, 0, stream>>>(
            (const float4*)user_emb, (float4*)user, n4);
        scatter_kernel<<<(NNZ + 3) / 4, 256, 0, stream>>>(
            vals, irows, icols, node, user, NNZ);
    }
}

// Round 8
// 181.747 us; speedup vs baseline: 1.0588x; 1.0588x over previous
//
#include <hip/hip_runtime.h>
#include <hip/hip_bf16.h>

constexpr int D        = 100;
constexpr int K        = 20;
constexpr int N_USER   = 50000;
constexpr int N_ENTITY = 60000;
constexpr int N_NEWS   = 20000;
constexpr int NNZ      = 500000;
constexpr int CAP      = 32;     // bucket capacity per user (avg degree = 10)
constexpr int N_NODE   = N_NEWS + N_ENTITY;
constexpr int HS       = 64;     // half-row stride (elems) = 128 B = 1 line

// ---- bf16 helpers ---------------------------------------------------------
static __device__ __forceinline__ unsigned short f2b(float x) {
    union { float f; unsigned int u; } c; c.f = x;
    unsigned int u = c.u;
    return (unsigned short)((u + 0x7FFFu + ((u >> 16) & 1u)) >> 16);
}
static __device__ __forceinline__ float blo(unsigned int t) {
    union { unsigned int u; float f; } c; c.u = t << 16; return c.f;
}
static __device__ __forceinline__ float bhi(unsigned int t) {
    union { unsigned int u; float f; } c; c.u = t & 0xFFFF0000u; return c.f;
}

// ---------------------------------------------------------------------------
// prep: f32 -> bf16 column-split tables (lo = elems 0..63, hi = 64..99 + pad)
// + zero counts + zero overflow-list counter.
// ---------------------------------------------------------------------------
constexpr int CVT_T = N_ENTITY * 32;

__global__ __launch_bounds__(256) void prep_kernel(
    const float* __restrict__ ent, const float* __restrict__ all,
    ushort4* __restrict__ entLo4, ushort4* __restrict__ entHi4,
    ushort4* __restrict__ allLo4, ushort4* __restrict__ allHi4,
    int* __restrict__ counts, int* __restrict__ listcnt)
{
    int i = (int)(blockIdx.x * blockDim.x + threadIdx.x);
    if (i < 2 * CVT_T) {
        bool isEnt = i < CVT_T;
        const float* src = isEnt ? ent : all;
        int j    = isEnt ? i : i - CVT_T;
        int row  = j >> 5;
        int slot = j & 31;
        int e = (slot < 16) ? slot * 4 : 64 + (slot - 16) * 4;
        ushort4 o = make_ushort4(0, 0, 0, 0);
        if (e < D) {
            const float* sp = src + (size_t)row * D + e;
            float v0 = __builtin_nontemporal_load(sp + 0);
            float v1 = __builtin_nontemporal_load(sp + 1);
            float v2 = __builtin_nontemporal_load(sp + 2);
            float v3 = __builtin_nontemporal_load(sp + 3);
            o.x = f2b(v0); o.y = f2b(v1); o.z = f2b(v2); o.w = f2b(v3);
        }
        ushort4* dst = isEnt ? ((slot < 16) ? entLo4 : entHi4)
                             : ((slot < 16) ? allLo4 : allHi4);
        dst[(size_t)row * 16 + (slot & 15)] = o;
    } else {
        int j = i - 2 * CVT_T;
        if (j < N_USER) counts[j] = 0;
        else if (j == N_USER) *listcnt = 0;
    }
}

// ---------------------------------------------------------------------------
// Bucket build: counts + interleaved (col,val) int2 fill + overflow list
// ---------------------------------------------------------------------------
__global__ __launch_bounds__(256) void hist_fill_kernel(
    const int* __restrict__ rows, const int* __restrict__ cols,
    const float* __restrict__ vals,
    int* __restrict__ counts, int2* __restrict__ bpair,
    int* __restrict__ list, int* __restrict__ listcnt, int nnz)
{
    int j = (int)(blockIdx.x * blockDim.x + threadIdx.x);
    if (j >= nnz) return;
    int r   = __builtin_nontemporal_load(rows + j);
    int pos = atomicAdd(&counts[r], 1);
    if (pos < CAP) {
        int   c = __builtin_nontemporal_load(cols + j);
        float v = __builtin_nontemporal_load(vals + j);
        bpair[(size_t)r * CAP + pos] = make_int2(c, __float_as_int(v));
    } else {
        int s = atomicAdd(listcnt, 1);
        list[s] = j;
    }
}

// ---------------------------------------------------------------------------
// Phase-split neighbor-sum aggregation; ONE PHASE PER LAUNCH (hard barrier
// between phases -> per-phase gather working set is one 7.7 MB half-table).
// Dual-row waves: lanes 0-31 -> row 2p, lanes 32-63 -> row 2p+1; each
// half-row = 64 elems = one 128 B line.
//   PH=0: gathers lo half (elems 0..63);  PH=1: hi half (64..99 + pad)
// Writes f32 node (nt, required output) + full-line bf16 shadow half-rows.
// ---------------------------------------------------------------------------
template<int PH>
__global__ __launch_bounds__(256) void sumagg_ph_kernel(
    const unsigned short* __restrict__ tab,   // half-table for this phase
    const int*   __restrict__ idx_mat,        // n x K
    const float* __restrict__ base,           // f32 residual rows
    float*       __restrict__ node,           // f32 out rows (pre-offset)
    unsigned short* __restrict__ nodeP,       // bf16 half shadow (pre-offset)
    int n)
{
    int pair = (int)((blockIdx.x * blockDim.x + threadIdx.x) >> 6);
    int lane = threadIdx.x & 63;
    int li   = lane & 31;
    int sub  = lane >> 5;
    if (pair >= (n >> 1)) return;
    int row = pair * 2 + sub;

    int idxv = (li < K)
        ? __builtin_nontemporal_load(idx_mat + (size_t)row * K + li) : 0;

    unsigned int t[K];
    #pragma unroll
    for (int k = 0; k < K; ++k) {
        int col = __shfl(idxv, sub * 32 + k);
        t[k] = *(const unsigned int*)(tab + (size_t)col * HS + li * 2);
    }
    float a0 = 0.f, a1 = 0.f;
    #pragma unroll
    for (int k = 0; k < K; ++k) { a0 += blo(t[k]); a1 += bhi(t[k]); }

    unsigned int packed = 0;
    if (PH == 0) {
        int e = li * 2;
        const float* bp = base + (size_t)row * D + e;
        float b0 = __builtin_nontemporal_load(bp);
        float b1 = __builtin_nontemporal_load(bp + 1);
        float o0 = a0 + b0, o1 = a1 + b1;
        float* np = node + (size_t)row * D + e;
        __builtin_nontemporal_store(o0, np);
        __builtin_nontemporal_store(o1, np + 1);
        packed = (unsigned int)f2b(o0) | ((unsigned int)f2b(o1) << 16);
    } else if (li < 18) {            // elems 64..99 = 18 lanes x 2
        int e = 64 + li * 2;
        const float* bp = base + (size_t)row * D + e;
        float b0 = __builtin_nontemporal_load(bp);
        float b1 = __builtin_nontemporal_load(bp + 1);
        float o0 = a0 + b0, o1 = a1 + b1;
        float* np = node + (size_t)row * D + e;
        __builtin_nontemporal_store(o0, np);
        __builtin_nontemporal_store(o1, np + 1);
        packed = (unsigned int)f2b(o0) | ((unsigned int)f2b(o1) << 16);
    }
    // all 32 lanes store -> full 128 B line, no RFO
    *(unsigned int*)(nodeP + (size_t)row * HS + li * 2) = packed;
}

// ---------------------------------------------------------------------------
// Per-user aggregate over split node shadows. One wave per user; lanes 0-31
// read the lo line of each gathered row, lanes 32-63 the hi line (same total
// line volume as a 256 B row). Branch-free 8-batch staging.
// ---------------------------------------------------------------------------
__global__ __launch_bounds__(256) void user_agg_kernel(
    const int* __restrict__ counts, const int2* __restrict__ bpair,
    const unsigned short* __restrict__ nodeLo,
    const unsigned short* __restrict__ nodeHi,
    const float* __restrict__ user_emb, float* __restrict__ user)
{
    int u    = (int)((blockIdx.x * blockDim.x + threadIdx.x) >> 6);
    int lane = threadIdx.x & 63;
    if (u >= N_USER) return;

    int c = counts[u];
    if (c > CAP) c = CAP;

    int colv = 0; float valv = 0.f;
    if (lane < c) {
        int2 bp = bpair[(size_t)u * CAP + lane];
        colv = bp.x; valv = __int_as_float(bp.y);
    }
    int clampi = (c > 0) ? (c - 1) : 0;

    const unsigned short* tab = (lane < 32) ? nodeLo : nodeHi;
    int off = (lane & 31) * 2;

    float a0 = 0.f, a1 = 0.f;
    for (int e0 = 0; e0 < c; e0 += 8) {
        unsigned int t[8]; float v[8];
        #pragma unroll
        for (int e = 0; e < 8; ++e) {
            int ee = e0 + e;
            int es = (ee < clampi) ? ee : clampi;   // dup loads -> L1 hits
            int   col = __shfl(colv, es);
            float vv  = __shfl(valv, es);
            v[e] = (ee < c) ? vv : 0.f;
            t[e] = *(const unsigned int*)(tab + (size_t)col * HS + off);
        }
        #pragma unroll
        for (int e = 0; e < 8; ++e) { a0 += v[e] * blo(t[e]); a1 += v[e] * bhi(t[e]); }
    }
    // lanes 0..31 -> elems 0..63 ; lanes 32..49 -> elems 64..99
    int e = (lane < 32) ? lane * 2 : 64 + (lane - 32) * 2;
    if (e < D) {
        const float* up = user_emb + (size_t)u * D + e;
        float u0 = __builtin_nontemporal_load(up);
        float u1 = __builtin_nontemporal_load(up + 1);
        float* op = user + (size_t)u * D + e;
        __builtin_nontemporal_store(a0 + u0, op);
        __builtin_nontemporal_store(a1 + u1, op + 1);
    }
}

// ---------------------------------------------------------------------------
// Overflow drain: entries hist pushed past CAP (none expected). f32 node.
// ---------------------------------------------------------------------------
__global__ __launch_bounds__(256) void drain_kernel(
    const int* __restrict__ list, const int* __restrict__ listcnt,
    const int* __restrict__ rows, const int* __restrict__ cols,
    const float* __restrict__ vals, const float* __restrict__ node,
    float* __restrict__ user)
{
    int nw   = (int)((gridDim.x * blockDim.x) >> 6);
    int wid  = (int)((blockIdx.x * blockDim.x + threadIdx.x) >> 6);
    int lane = threadIdx.x & 63;
    int cnt  = *listcnt;
    if (cnt > NNZ) cnt = NNZ;
    for (int s = wid; s < cnt; s += nw) {
        int j = list[s];
        int   r = rows[j];
        int   c = cols[j];
        float v = vals[j];
        const float* src = node + (size_t)c * D;
        float*       dst = user + (size_t)r * D;
        unsafeAtomicAdd(&dst[lane], v * src[lane]);
        int l2 = lane + 64;
        if (l2 < D) unsafeAtomicAdd(&dst[l2], v * src[l2]);
    }
}

// ---------------------------------------------------------------------------
// Fallback tiers (f32; only if workspace too small — never hit in practice)
// ---------------------------------------------------------------------------
__global__ __launch_bounds__(256) void zero2_kernel(
    int* __restrict__ counts, int* __restrict__ listcnt, int n)
{
    int i = (int)(blockIdx.x * blockDim.x + threadIdx.x);
    if (i < n) counts[i] = 0;
    else if (i == n) *listcnt = 0;
}

__global__ __launch_bounds__(256) void sumagg_f32_kernel(
    const float* __restrict__ table, const int* __restrict__ idx_mat,
    const float* __restrict__ base, float* __restrict__ out, int n)
{
    int wave = (int)((blockIdx.x * blockDim.x + threadIdx.x) >> 6);
    int lane = threadIdx.x & 63;
    if (wave >= n) return;
    int idxv = (lane < K) ? idx_mat[(size_t)wave * K + lane] : 0;
    float acc0 = 0.f, acc1 = 0.f;
    int l2 = lane + 64;
    #pragma unroll
    for (int k = 0; k < K; ++k) {
        int ei = __shfl(idxv, k);
        const float* r = table + (size_t)ei * D;
        acc0 += r[lane];
        if (l2 < D) acc1 += r[l2];
    }
    const float* b = base + (size_t)wave * D;
    float*       o = out  + (size_t)wave * D;
    o[lane] = acc0 + b[lane];
    if (l2 < D) o[l2] = acc1 + b[l2];
}

__global__ __launch_bounds__(256) void user_agg_f32_kernel(
    const int* __restrict__ counts, const int2* __restrict__ bpair,
    const float* __restrict__ node,
    const float* __restrict__ user_emb, float* __restrict__ user)
{
    int u    = (int)((blockIdx.x * blockDim.x + threadIdx.x) >> 6);
    int lane = threadIdx.x & 63;
    if (u >= N_USER) return;
    int c = counts[u];
    if (c > CAP) c = CAP;
    int colv = 0; float valv = 0.f;
    if (lane < c) {
        int2 bp = bpair[(size_t)u * CAP + lane];
        colv = bp.x; valv = __int_as_float(bp.y);
    }
    float a0 = 0.f, a1 = 0.f;
    int l2 = lane + 64;
    for (int e = 0; e < c; ++e) {
        int   col = __shfl(colv, e);
        float v   = __shfl(valv, e);
        const float* r = node + (size_t)col * D;
        a0 += v * r[lane];
        if (l2 < D) a1 += v * r[l2];
    }
    const float* ue = user_emb + (size_t)u * D;
    float*       o  = user     + (size_t)u * D;
    o[lane] = a0 + ue[lane];
    if (l2 < D) o[l2] = a1 + ue[l2];
}

__global__ __launch_bounds__(256) void copy_kernel(
    const float4* __restrict__ src, float4* __restrict__ dst, int n4)
{
    int i = (int)(blockIdx.x * blockDim.x + threadIdx.x);
    if (i < n4) dst[i] = src[i];
}

__global__ __launch_bounds__(256) void scatter_kernel(
    const float* __restrict__ vals, const int* __restrict__ rows,
    const int* __restrict__ cols, const float* __restrict__ node,
    float* __restrict__ user, int nnz)
{
    int j    = (int)((blockIdx.x * blockDim.x + threadIdx.x) >> 6);
    int lane = threadIdx.x & 63;
    if (j >= nnz) return;
    int   r = rows[j];
    int   c = cols[j];
    float v = vals[j];
    const float* src = node + (size_t)c * D;
    float*       dst = user + (size_t)r * D;
    unsafeAtomicAdd(&dst[lane], v * src[lane]);
    int l2 = lane + 64;
    if (l2 < D) unsafeAtomicAdd(&dst[l2], v * src[l2]);
}

// ---------------------------------------------------------------------------
extern "C" void kernel_launch(void* const* d_in, const int* in_sizes, int n_in,
                              void* d_out, int out_size, void* d_ws, size_t ws_size,
                              hipStream_t stream)
{
    const float* user_emb = (const float*)d_in[0];
    const float* all_emb  = (const float*)d_in[1];
    const float* ent_emb  = (const float*)d_in[2];
    // d_in[3..7]: relation_emb, W_news, b_news, W_ent, b_ent — dead inputs
    // (softmax over a size-1 axis is identically 1.0 in the reference).
    const float* vals     = (const float*)d_in[8];
    const int*   news_ent = (const int*)d_in[9];
    const int*   ngh_ent  = (const int*)d_in[11];
    const int*   irows    = (const int*)d_in[13];
    const int*   icols    = (const int*)d_in[14];

    float* node = (float*)d_out;                         // 80000 x 100
    float* user = (float*)d_out + (size_t)N_NODE * D;    // 50000 x 100

    // workspace layout (tier A)
    int*   counts  = (int*)d_ws;                              // N_USER
    int*   list    = counts + N_USER;                         // NNZ
    int*   listcnt = list + NNZ;                              // 1 (+63 pad)
    int2*  bpair   = (int2*)(listcnt + 64);                   // N_USER*CAP int2
    unsigned short* entLo  = (unsigned short*)(bpair + (size_t)N_USER * CAP);
    unsigned short* entHi  = entLo  + (size_t)N_ENTITY * HS;
    unsigned short* allLo  = entHi  + (size_t)N_ENTITY * HS;
    unsigned short* allHi  = allLo  + (size_t)N_ENTITY * HS;
    unsigned short* nodeLo = allHi  + (size_t)N_ENTITY * HS;
    unsigned short* nodeHi = nodeLo + (size_t)N_NODE * HS;

    size_t need_bucket = ((size_t)N_USER + NNZ + 64) * 4ull
                       + (size_t)N_USER * CAP * 8ull;
    size_t need_full   = need_bucket
                       + (4ull * N_ENTITY * HS + 2ull * N_NODE * HS) * 2ull;

    if (ws_size >= need_full) {
        // ---- tier A: phase-split bf16 gathers, one launch per phase ----
        int prep_n = 2 * CVT_T + N_USER + 1;
        prep_kernel<<<(prep_n + 255) / 256, 256, 0, stream>>>(
            ent_emb, all_emb, (ushort4*)entLo, (ushort4*)entHi,
            (ushort4*)allLo, (ushort4*)allHi, counts, listcnt);
        hist_fill_kernel<<<(NNZ + 255) / 256, 256, 0, stream>>>(
            irows, icols, vals, counts, bpair, list, listcnt, NNZ);

        // news: gathers bf16(entity_emb); 2 waves of rows per wave -> /8
        sumagg_ph_kernel<0><<<(N_NEWS / 2 + 3) / 4, 256, 0, stream>>>(
            entLo, news_ent, all_emb, node, nodeLo, N_NEWS);
        sumagg_ph_kernel<1><<<(N_NEWS / 2 + 3) / 4, 256, 0, stream>>>(
            entHi, news_ent, all_emb, node, nodeHi, N_NEWS);
        // entity: gathers bf16(all_embedding)
        sumagg_ph_kernel<0><<<(N_ENTITY / 2 + 3) / 4, 256, 0, stream>>>(
            allLo, ngh_ent, all_emb, node + (size_t)N_NEWS * D,
            nodeLo + (size_t)N_NEWS * HS, N_ENTITY);
        sumagg_ph_kernel<1><<<(N_ENTITY / 2 + 3) / 4, 256, 0, stream>>>(
            allHi, ngh_ent, all_emb, node + (size_t)N_NEWS * D,
            nodeHi + (size_t)N_NEWS * HS, N_ENTITY);

        user_agg_kernel<<<(N_USER + 3) / 4, 256, 0, stream>>>(
            counts, bpair, nodeLo, nodeHi, user_emb, user);
        drain_kernel<<<64, 256, 0, stream>>>(
            list, listcnt, irows, icols, vals, node, user);
    } else if (ws_size >= need_bucket) {
        // ---- tier B: f32 bucket-gather ----
        sumagg_f32_kernel<<<(N_NEWS + 3) / 4, 256, 0, stream>>>(
            ent_emb, news_ent, all_emb, node, N_NEWS);
        sumagg_f32_kernel<<<(N_ENTITY + 3) / 4, 256, 0, stream>>>(
            all_emb, ngh_ent, all_emb, node + (size_t)N_NEWS * D, N_ENTITY);
        zero2_kernel<<<(N_USER + 256) / 256, 256, 0, stream>>>(
            counts, listcnt, N_USER);
        hist_fill_kernel<<<(NNZ + 255) / 256, 256, 0, stream>>>(
            irows, icols, vals, counts, bpair, list, listcnt, NNZ);
        user_agg_f32_kernel<<<(N_USER + 3) / 4, 256, 0, stream>>>(
            counts, bpair, node, user_emb, user);
        drain_kernel<<<64, 256, 0, stream>>>(
            list, listcnt, irows, icols, vals, node, user);
    } else {
        // ---- tier C: atomic scatter ----
        sumagg_f32_kernel<<<(N_NEWS + 3) / 4, 256, 0, stream>>>(
            ent_emb, news_ent, all_emb, node, N_NEWS);
        sumagg_f32_kernel<<<(N_ENTITY + 3) / 4, 256, 0, stream>>>(
            all_emb, ngh_ent, all_emb, node + (size_t)N_NEWS * D, N_ENTITY);
        int n4 = N_USER * D / 4;
        copy_kernel<<<(n4 + 255) / 256, 256, 0, stream>>>(
            (const float4*)user_emb, (float4*)user, n4);
        scatter_kernel<<<(NNZ + 3) / 4, 256, 0, stream>>>(
            vals, irows, icols, node, user, NNZ);
    }
}

// Round 10
// 134.625 us; speedup vs baseline: 1.4294x; 1.3500x over previous
//
#include <hip/hip_runtime.h>
#include <hip/hip_bf16.h>

constexpr int D        = 100;
constexpr int K        = 20;
constexpr int N_USER   = 50000;
constexpr int N_ENTITY = 60000;
constexpr int N_NEWS   = 20000;
constexpr int NNZ      = 500000;
constexpr int CAP      = 32;     // bucket capacity per user (avg degree = 10)
constexpr int N_NODE   = N_NEWS + N_ENTITY;
constexpr int TS       = 128;    // bf16 node-shadow row stride (elems) = 256 B
constexpr int FS       = 32;     // int8 table row stride in uints (128 B = 1 line)

// ---- bf16 helpers ---------------------------------------------------------
static __device__ __forceinline__ unsigned short f2b(float x) {
    union { float f; unsigned int u; } c; c.f = x;
    unsigned int u = c.u;
    return (unsigned short)((u + 0x7FFFu + ((u >> 16) & 1u)) >> 16);
}
static __device__ __forceinline__ float blo(unsigned int t) {
    union { unsigned int u; float f; } c; c.u = t << 16; return c.f;
}
static __device__ __forceinline__ float bhi(unsigned int t) {
    union { unsigned int u; float f; } c; c.u = t & 0xFFFF0000u; return c.f;
}

// ---------------------------------------------------------------------------
// prep: f32 -> per-row-scaled int8 tables. Row layout (128 B = 1 line):
//   bytes 0..99   : int8 quantized elems (q = round(x * 127/rowmax))
//   bytes 100..103: f32 dequant scale (rowmax/127)
//   bytes 104..127: zero pad
// One 32-lane half-wave per row (lanes li<25 handle 4 elems each; lane 25
// stores the scale). Tail thread range zeroes counts + overflow counter.
// ---------------------------------------------------------------------------
constexpr int PREP_WAVES = N_ENTITY;              // /2 rows * 2 tables
constexpr int PREP_ROWT  = PREP_WAVES * 64;       // row-work threads

__global__ __launch_bounds__(256) void prep_kernel(
    const float* __restrict__ ent, const float* __restrict__ all,
    unsigned int* __restrict__ entQ, unsigned int* __restrict__ allQ,
    int* __restrict__ counts, int* __restrict__ listcnt)
{
    int i = (int)(blockIdx.x * blockDim.x + threadIdx.x);
    if (i < PREP_ROWT) {
        int w    = i >> 6;
        int lane = i & 63;
        int li   = lane & 31;
        int sub  = lane >> 5;
        bool isEnt = w < PREP_WAVES / 2;
        const float* src = isEnt ? ent : all;
        unsigned int* dst = isEnt ? entQ : allQ;
        int row = 2 * (isEnt ? w : (w - PREP_WAVES / 2)) + sub;

        float v0 = 0.f, v1 = 0.f, v2 = 0.f, v3 = 0.f, lmax = 0.f;
        if (li < 25) {
            const float* sp = src + (size_t)row * D + li * 4;
            v0 = __builtin_nontemporal_load(sp + 0);
            v1 = __builtin_nontemporal_load(sp + 1);
            v2 = __builtin_nontemporal_load(sp + 2);
            v3 = __builtin_nontemporal_load(sp + 3);
            lmax = fmaxf(fmaxf(fabsf(v0), fabsf(v1)),
                         fmaxf(fabsf(v2), fabsf(v3)));
        }
        // half-wave max reduce (offsets 16..1 stay within the 32-lane group)
        #pragma unroll
        for (int off = 16; off >= 1; off >>= 1)
            lmax = fmaxf(lmax, __shfl_xor(lmax, off));

        float inv = (lmax > 0.f) ? (127.0f / lmax) : 0.f;
        unsigned int o = 0;
        if (li < 25) {
            int q0 = (int)rintf(v0 * inv);
            int q1 = (int)rintf(v1 * inv);
            int q2 = (int)rintf(v2 * inv);
            int q3 = (int)rintf(v3 * inv);
            o = ((unsigned int)(unsigned char)(signed char)q0)
              | ((unsigned int)(unsigned char)(signed char)q1 << 8)
              | ((unsigned int)(unsigned char)(signed char)q2 << 16)
              | ((unsigned int)(unsigned char)(signed char)q3 << 24);
        } else if (li == 25) {
            o = __float_as_uint(lmax * (1.0f / 127.0f));
        }
        dst[(size_t)row * FS + li] = o;
    } else {
        int j = i - PREP_ROWT;
        if (j < N_USER) counts[j] = 0;
        else if (j == N_USER) *listcnt = 0;
    }
}

// ---------------------------------------------------------------------------
// Bucket build: counts + packed (col:17b | val:15b fixed) fill + overflow list
// ---------------------------------------------------------------------------
__global__ __launch_bounds__(256) void hist_fill_kernel(
    const int* __restrict__ rows, const int* __restrict__ cols,
    const float* __restrict__ vals,
    int* __restrict__ counts, unsigned int* __restrict__ bpack,
    int* __restrict__ list, int* __restrict__ listcnt, int nnz)
{
    int j = (int)(blockIdx.x * blockDim.x + threadIdx.x);
    if (j >= nnz) return;
    int r   = __builtin_nontemporal_load(rows + j);
    int pos = atomicAdd(&counts[r], 1);
    if (pos < CAP) {
        int   c = __builtin_nontemporal_load(cols + j);
        float v = __builtin_nontemporal_load(vals + j);
        int q = (int)(v * 32767.0f + 0.5f);
        if (q > 32767) q = 32767;
        if (q < 0) q = 0;
        bpack[(size_t)r * CAP + pos] = (unsigned int)c | ((unsigned int)q << 17);
    } else {
        int s = atomicAdd(listcnt, 1);
        list[s] = j;
    }
}

// ---------------------------------------------------------------------------
// Neighbor-sum aggregation (softmax over size-1 axis == 1.0), per-row-scaled
// int8 gather table, ONE 128 B line per row. Dual-row waves (lanes 0-31 ->
// row 2p, 32-63 -> 2p+1); lane li holds elems 4li..4li+3; scale is broadcast
// from lane (sub*32+25)'s gathered word — zero extra loads.
// Writes f32 node (nt) + bf16 TS=128 shadow (full 256 B line, zero pad).
// ---------------------------------------------------------------------------
__global__ __launch_bounds__(256) void sumagg_q8_kernel(
    const unsigned int* __restrict__ tabQ,
    const int*   __restrict__ idx_mat,   // n x K
    const float* __restrict__ base,      // f32 residual rows (pre-offset)
    float*       __restrict__ node,      // f32 out rows (pre-offset)
    unsigned short* __restrict__ nodeB,  // bf16 shadow rows (pre-offset)
    int n)
{
    int pair = (int)((blockIdx.x * blockDim.x + threadIdx.x) >> 6);
    int lane = threadIdx.x & 63;
    int li   = lane & 31;
    int sub  = lane >> 5;
    if (pair >= (n >> 1)) return;
    int row = pair * 2 + sub;

    int idxv = (li < K)
        ? __builtin_nontemporal_load(idx_mat + (size_t)row * K + li) : 0;

    unsigned int t[K];
    #pragma unroll
    for (int k = 0; k < K; ++k) {
        int col = __shfl(idxv, sub * 32 + k);
        t[k] = tabQ[(size_t)col * FS + li];
    }

    float a0 = 0.f, a1 = 0.f, a2 = 0.f, a3 = 0.f;
    #pragma unroll
    for (int k = 0; k < K; ++k) {
        float sc = __uint_as_float((unsigned int)__shfl((int)t[k], sub * 32 + 25));
        unsigned int u = t[k];
        a0 += (float)((signed char)(u       & 0xFF)) * sc;
        a1 += (float)((signed char)((u >> 8) & 0xFF)) * sc;
        a2 += (float)((signed char)((u >> 16) & 0xFF)) * sc;
        a3 += (float)((int)u >> 24) * sc;
    }

    // lane li covers elems 4li..4li+3 ; active for li<25 (100 elems)
    unsigned int p0 = 0, p1 = 0;
    if (li < 25) {
        const float* bp = base + (size_t)row * D + li * 4;
        float o0 = a0 + __builtin_nontemporal_load(bp + 0);
        float o1 = a1 + __builtin_nontemporal_load(bp + 1);
        float o2 = a2 + __builtin_nontemporal_load(bp + 2);
        float o3 = a3 + __builtin_nontemporal_load(bp + 3);
        float* np = node + (size_t)row * D + li * 4;
        __builtin_nontemporal_store(o0, np + 0);
        __builtin_nontemporal_store(o1, np + 1);
        __builtin_nontemporal_store(o2, np + 2);
        __builtin_nontemporal_store(o3, np + 3);
        p0 = (unsigned int)f2b(o0) | ((unsigned int)f2b(o1) << 16);
        p1 = (unsigned int)f2b(o2) | ((unsigned int)f2b(o3) << 16);
    }
    // 32 lanes x 8 B = full 256 B shadow row (pad lanes write zeros)
    unsigned int* sb = (unsigned int*)(nodeB + (size_t)row * TS + li * 4);
    sb[0] = p0; sb[1] = p1;
}

// ---------------------------------------------------------------------------
// Per-user aggregate, bf16 TS=128 node gather, packed buckets, branch-free
// 8-batch staging.  user[u,:] = user_emb[u,:] + sum vals*nodeB[cols,:]
// ---------------------------------------------------------------------------
__global__ __launch_bounds__(256) void user_agg_kernel(
    const int* __restrict__ counts, const unsigned int* __restrict__ bpack,
    const unsigned short* __restrict__ nodeB,
    const float* __restrict__ user_emb, float* __restrict__ user)
{
    int u    = (int)((blockIdx.x * blockDim.x + threadIdx.x) >> 6);
    int lane = threadIdx.x & 63;
    if (u >= N_USER) return;

    int c = counts[u];
    if (c > CAP) c = CAP;

    int colv = 0; float valv = 0.f;
    if (lane < c) {
        unsigned int pk = __builtin_nontemporal_load(bpack + (size_t)u * CAP + lane);
        colv = (int)(pk & 0x1FFFFu);
        valv = (float)(pk >> 17) * (1.0f / 32767.0f);
    }
    int clampi = (c > 0) ? (c - 1) : 0;

    float a0 = 0.f, a1 = 0.f;
    for (int e0 = 0; e0 < c; e0 += 8) {
        unsigned int t[8]; float v[8];
        #pragma unroll
        for (int e = 0; e < 8; ++e) {
            int ee = e0 + e;
            int es = (ee < clampi) ? ee : clampi;   // dup loads -> L1 hits
            int   col = __shfl(colv, es);
            float vv  = __shfl(valv, es);
            v[e] = (ee < c) ? vv : 0.f;
            t[e] = *(const unsigned int*)(nodeB + (size_t)col * TS + lane * 2);
        }
        #pragma unroll
        for (int e = 0; e < 8; ++e) { a0 += v[e] * blo(t[e]); a1 += v[e] * bhi(t[e]); }
    }
    if (lane < D / 2) {
        const float* up = user_emb + (size_t)u * D + lane * 2;
        float u0 = __builtin_nontemporal_load(up);
        float u1 = __builtin_nontemporal_load(up + 1);
        float* op = user + (size_t)u * D + lane * 2;
        __builtin_nontemporal_store(a0 + u0, op);
        __builtin_nontemporal_store(a1 + u1, op + 1);
    }
}

// ---------------------------------------------------------------------------
// Overflow drain: entries hist pushed past CAP (none expected). f32 node.
// ---------------------------------------------------------------------------
__global__ __launch_bounds__(256) void drain_kernel(
    const int* __restrict__ list, const int* __restrict__ listcnt,
    const int* __restrict__ rows, const int* __restrict__ cols,
    const float* __restrict__ vals, const float* __restrict__ node,
    float* __restrict__ user)
{
    int nw   = (int)((gridDim.x * blockDim.x) >> 6);
    int wid  = (int)((blockIdx.x * blockDim.x + threadIdx.x) >> 6);
    int lane = threadIdx.x & 63;
    int cnt  = *listcnt;
    if (cnt > NNZ) cnt = NNZ;
    for (int s = wid; s < cnt; s += nw) {
        int j = list[s];
        int   r = rows[j];
        int   c = cols[j];
        float v = vals[j];
        const float* src = node + (size_t)c * D;
        float*       dst = user + (size_t)r * D;
        unsafeAtomicAdd(&dst[lane], v * src[lane]);
        int l2 = lane + 64;
        if (l2 < D) unsafeAtomicAdd(&dst[l2], v * src[l2]);
    }
}

// ---------------------------------------------------------------------------
// Fallback tiers (f32; only if workspace too small — never hit in practice)
// ---------------------------------------------------------------------------
__global__ __launch_bounds__(256) void zero2_kernel(
    int* __restrict__ counts, int* __restrict__ listcnt, int n)
{
    int i = (int)(blockIdx.x * blockDim.x + threadIdx.x);
    if (i < n) counts[i] = 0;
    else if (i == n) *listcnt = 0;
}

__global__ __launch_bounds__(256) void sumagg_f32_kernel(
    const float* __restrict__ table, const int* __restrict__ idx_mat,
    const float* __restrict__ base, float* __restrict__ out, int n)
{
    int wave = (int)((blockIdx.x * blockDim.x + threadIdx.x) >> 6);
    int lane = threadIdx.x & 63;
    if (wave >= n) return;
    int idxv = (lane < K) ? idx_mat[(size_t)wave * K + lane] : 0;
    float acc0 = 0.f, acc1 = 0.f;
    int l2 = lane + 64;
    #pragma unroll
    for (int k = 0; k < K; ++k) {
        int ei = __shfl(idxv, k);
        const float* r = table + (size_t)ei * D;
        acc0 += r[lane];
        if (l2 < D) acc1 += r[l2];
    }
    const float* b = base + (size_t)wave * D;
    float*       o = out  + (size_t)wave * D;
    o[lane] = acc0 + b[lane];
    if (l2 < D) o[l2] = acc1 + b[l2];
}

__global__ __launch_bounds__(256) void user_agg_f32_kernel(
    const int* __restrict__ counts, const unsigned int* __restrict__ bpack,
    const float* __restrict__ node,
    const float* __restrict__ user_emb, float* __restrict__ user)
{
    int u    = (int)((blockIdx.x * blockDim.x + threadIdx.x) >> 6);
    int lane = threadIdx.x & 63;
    if (u >= N_USER) return;
    int c = counts[u];
    if (c > CAP) c = CAP;
    int colv = 0; float valv = 0.f;
    if (lane < c) {
        unsigned int pk = bpack[(size_t)u * CAP + lane];
        colv = (int)(pk & 0x1FFFFu);
        valv = (float)(pk >> 17) * (1.0f / 32767.0f);
    }
    float a0 = 0.f, a1 = 0.f;
    int l2 = lane + 64;
    for (int e = 0; e < c; ++e) {
        int   col = __shfl(colv, e);
        float v   = __shfl(valv, e);
        const float* r = node + (size_t)col * D;
        a0 += v * r[lane];
        if (l2 < D) a1 += v * r[l2];
    }
    const float* ue = user_emb + (size_t)u * D;
    float*       o  = user     + (size_t)u * D;
    o[lane] = a0 + ue[lane];
    if (l2 < D) o[l2] = a1 + ue[l2];
}

__global__ __launch_bounds__(256) void copy_kernel(
    const float4* __restrict__ src, float4* __restrict__ dst, int n4)
{
    int i = (int)(blockIdx.x * blockDim.x + threadIdx.x);
    if (i < n4) dst[i] = src[i];
}

__global__ __launch_bounds__(256) void scatter_kernel(
    const float* __restrict__ vals, const int* __restrict__ rows,
    const int* __restrict__ cols, const float* __restrict__ node,
    float* __restrict__ user, int nnz)
{
    int j    = (int)((blockIdx.x * blockDim.x + threadIdx.x) >> 6);
    int lane = threadIdx.x & 63;
    if (j >= nnz) return;
    int   r = rows[j];
    int   c = cols[j];
    float v = vals[j];
    const float* src = node + (size_t)c * D;
    float*       dst = user + (size_t)r * D;
    unsafeAtomicAdd(&dst[lane], v * src[lane]);
    int l2 = lane + 64;
    if (l2 < D) unsafeAtomicAdd(&dst[l2], v * src[l2]);
}

// ---------------------------------------------------------------------------
extern "C" void kernel_launch(void* const* d_in, const int* in_sizes, int n_in,
                              void* d_out, int out_size, void* d_ws, size_t ws_size,
                              hipStream_t stream)
{
    const float* user_emb = (const float*)d_in[0];
    const float* all_emb  = (const float*)d_in[1];
    const float* ent_emb  = (const float*)d_in[2];
    // d_in[3..7]: relation_emb, W_news, b_news, W_ent, b_ent — dead inputs
    // (softmax over a size-1 axis is identically 1.0 in the reference).
    const float* vals     = (const float*)d_in[8];
    const int*   news_ent = (const int*)d_in[9];
    const int*   ngh_ent  = (const int*)d_in[11];
    const int*   irows    = (const int*)d_in[13];
    const int*   icols    = (const int*)d_in[14];

    float* node = (float*)d_out;                         // 80000 x 100
    float* user = (float*)d_out + (size_t)N_NODE * D;    // 50000 x 100

    // workspace layout (tier A)
    int*   counts  = (int*)d_ws;                              // N_USER
    int*   list    = counts + N_USER;                         // NNZ
    int*   listcnt = list + NNZ;                              // 1 (+63 pad)
    unsigned int* bpack = (unsigned int*)(listcnt + 64);      // N_USER*CAP
    unsigned int* entQ  = bpack + (size_t)N_USER * CAP;       // N_ENTITY*FS
    unsigned int* allQ  = entQ + (size_t)N_ENTITY * FS;       // N_ENTITY*FS
    unsigned short* nodeB = (unsigned short*)(allQ + (size_t)N_ENTITY * FS);

    size_t need_bucket = ((size_t)N_USER + NNZ + 64 + (size_t)N_USER * CAP) * 4ull;
    size_t need_full   = need_bucket
                       + 2ull * N_ENTITY * FS * 4ull          // int8 tables
                       + (size_t)N_NODE * TS * 2ull;          // bf16 shadow

    if (ws_size >= need_full) {
        // ---- tier A: per-row-scaled int8 single-line gathers ----
        int prep_n = PREP_ROWT + N_USER + 1;
        prep_kernel<<<(prep_n + 255) / 256, 256, 0, stream>>>(
            ent_emb, all_emb, entQ, allQ, counts, listcnt);
        hist_fill_kernel<<<(NNZ + 255) / 256, 256, 0, stream>>>(
            irows, icols, vals, counts, bpack, list, listcnt, NNZ);

        // news: gathers q8(entity_emb); dual-row waves -> n/2 waves
        sumagg_q8_kernel<<<(N_NEWS / 2 + 3) / 4, 256, 0, stream>>>(
            entQ, news_ent, all_emb, node, nodeB, N_NEWS);
        // entity: gathers q8(all_embedding)
        sumagg_q8_kernel<<<(N_ENTITY / 2 + 3) / 4, 256, 0, stream>>>(
            allQ, ngh_ent, all_emb, node + (size_t)N_NEWS * D,
            nodeB + (size_t)N_NEWS * TS, N_ENTITY);

        user_agg_kernel<<<(N_USER + 3) / 4, 256, 0, stream>>>(
            counts, bpack, nodeB, user_emb, user);
        drain_kernel<<<64, 256, 0, stream>>>(
            list, listcnt, irows, icols, vals, node, user);
    } else if (ws_size >= need_bucket) {
        // ---- tier B: f32 bucket-gather ----
        sumagg_f32_kernel<<<(N_NEWS + 3) / 4, 256, 0, stream>>>(
            ent_emb, news_ent, all_emb, node, N_NEWS);
        sumagg_f32_kernel<<<(N_ENTITY + 3) / 4, 256, 0, stream>>>(
            all_emb, ngh_ent, all_emb, node + (size_t)N_NEWS * D, N_ENTITY);
        zero2_kernel<<<(N_USER + 256) / 256, 256, 0, stream>>>(
            counts, listcnt, N_USER);
        hist_fill_kernel<<<(NNZ + 255) / 256, 256, 0, stream>>>(
            irows, icols, vals, counts, bpack, list, listcnt, NNZ);
        user_agg_f32_kernel<<<(N_USER + 3) / 4, 256, 0, stream>>>(
            counts, bpack, node, user_emb, user);
        drain_kernel<<<64, 256, 0, stream>>>(
            list, listcnt, irows, icols, vals, node, user);
    } else {
        // ---- tier C: atomic scatter ----
        sumagg_f32_kernel<<<(N_NEWS + 3) / 4, 256, 0, stream>>>(
            ent_emb, news_ent, all_emb, node, N_NEWS);
        sumagg_f32_kernel<<<(N_ENTITY + 3) / 4, 256, 0, stream>>>(
            all_emb, ngh_ent, all_emb, node + (size_t)N_NEWS * D, N_ENTITY);
        int n4 = N_USER * D / 4;
        copy_kernel<<<(n4 + 255) / 256, 256, 0, stream>>>(
            (const float4*)user_emb, (float4*)user, n4);
        scatter_kernel<<<(NNZ + 3) / 4, 256, 0, stream>>>(
            vals, irows, icols, node, user, NNZ);
    }
}

// Round 11
// 128.323 us; speedup vs baseline: 1.4996x; 1.0491x over previous
//
#include <hip/hip_runtime.h>
#include <hip/hip_bf16.h>

constexpr int D        = 100;
constexpr int K        = 20;
constexpr int N_USER   = 50000;
constexpr int N_ENTITY = 60000;
constexpr int N_NEWS   = 20000;
constexpr int NNZ      = 500000;
constexpr int CAP      = 32;     // bucket capacity per user (avg degree = 10)
constexpr int N_NODE   = N_NEWS + N_ENTITY;
constexpr int FS       = 32;     // int8 row stride in uints (128 B = 1 line)

// ---------------------------------------------------------------------------
// prep: f32 -> per-row-scaled int8 tables. Row layout (128 B = 1 line):
//   bytes 0..99   : int8 quantized elems (q = round(x * 127/rowmax))
//   bytes 100..103: f32 dequant scale (rowmax/127)
//   bytes 104..127: zero pad
// One 32-lane half-wave per row. Tail threads zero counts + overflow counter.
// ---------------------------------------------------------------------------
constexpr int PREP_WAVES = N_ENTITY;              // /2 rows * 2 tables
constexpr int PREP_ROWT  = PREP_WAVES * 64;       // row-work threads

__global__ __launch_bounds__(256) void prep_kernel(
    const float* __restrict__ ent, const float* __restrict__ all,
    unsigned int* __restrict__ entQ, unsigned int* __restrict__ allQ,
    int* __restrict__ counts, int* __restrict__ listcnt)
{
    int i = (int)(blockIdx.x * blockDim.x + threadIdx.x);
    if (i < PREP_ROWT) {
        int w    = i >> 6;
        int lane = i & 63;
        int li   = lane & 31;
        int sub  = lane >> 5;
        bool isEnt = w < PREP_WAVES / 2;
        const float* src = isEnt ? ent : all;
        unsigned int* dst = isEnt ? entQ : allQ;
        int row = 2 * (isEnt ? w : (w - PREP_WAVES / 2)) + sub;

        float v0 = 0.f, v1 = 0.f, v2 = 0.f, v3 = 0.f, lmax = 0.f;
        if (li < 25) {
            const float* sp = src + (size_t)row * D + li * 4;
            v0 = __builtin_nontemporal_load(sp + 0);
            v1 = __builtin_nontemporal_load(sp + 1);
            v2 = __builtin_nontemporal_load(sp + 2);
            v3 = __builtin_nontemporal_load(sp + 3);
            lmax = fmaxf(fmaxf(fabsf(v0), fabsf(v1)),
                         fmaxf(fabsf(v2), fabsf(v3)));
        }
        #pragma unroll
        for (int off = 16; off >= 1; off >>= 1)
            lmax = fmaxf(lmax, __shfl_xor(lmax, off));

        float inv = (lmax > 0.f) ? (127.0f / lmax) : 0.f;
        unsigned int o = 0;
        if (li < 25) {
            int q0 = (int)rintf(v0 * inv);
            int q1 = (int)rintf(v1 * inv);
            int q2 = (int)rintf(v2 * inv);
            int q3 = (int)rintf(v3 * inv);
            o = ((unsigned int)(unsigned char)(signed char)q0)
              | ((unsigned int)(unsigned char)(signed char)q1 << 8)
              | ((unsigned int)(unsigned char)(signed char)q2 << 16)
              | ((unsigned int)(unsigned char)(signed char)q3 << 24);
        } else if (li == 25) {
            o = __float_as_uint(lmax * (1.0f / 127.0f));
        }
        dst[(size_t)row * FS + li] = o;
    } else {
        int j = i - PREP_ROWT;
        if (j < N_USER) counts[j] = 0;
        else if (j == N_USER) *listcnt = 0;
    }
}

// ---------------------------------------------------------------------------
// Bucket build: counts + packed (col:17b | val:15b fixed) fill + overflow list
// ---------------------------------------------------------------------------
__global__ __launch_bounds__(256) void hist_fill_kernel(
    const int* __restrict__ rows, const int* __restrict__ cols,
    const float* __restrict__ vals,
    int* __restrict__ counts, unsigned int* __restrict__ bpack,
    int* __restrict__ list, int* __restrict__ listcnt, int nnz)
{
    int j = (int)(blockIdx.x * blockDim.x + threadIdx.x);
    if (j >= nnz) return;
    int r   = __builtin_nontemporal_load(rows + j);
    int pos = atomicAdd(&counts[r], 1);
    if (pos < CAP) {
        int   c = __builtin_nontemporal_load(cols + j);
        float v = __builtin_nontemporal_load(vals + j);
        int q = (int)(v * 32767.0f + 0.5f);
        if (q > 32767) q = 32767;
        if (q < 0) q = 0;
        bpack[(size_t)r * CAP + pos] = (unsigned int)c | ((unsigned int)q << 17);
    } else {
        int s = atomicAdd(listcnt, 1);
        list[s] = j;
    }
}

// ---------------------------------------------------------------------------
// Neighbor-sum aggregation (softmax over size-1 axis == 1.0), per-row-scaled
// int8 gather table (one 128 B line/row). Dual-row waves; lane li holds elems
// 4li..4li+3; gathered row scale broadcast from slot 25 of the same line.
// Writes f32 node (nt, output 0) + per-row-scaled int8 shadow nodeQ (one
// 128 B line/row) for the user gather.
// ---------------------------------------------------------------------------
__global__ __launch_bounds__(256) void sumagg_q8_kernel(
    const unsigned int* __restrict__ tabQ,
    const int*   __restrict__ idx_mat,   // n x K
    const float* __restrict__ base,      // f32 residual rows (pre-offset)
    float*       __restrict__ node,      // f32 out rows (pre-offset)
    unsigned int* __restrict__ nodeQ,    // int8 shadow rows (pre-offset)
    int n)
{
    int pair = (int)((blockIdx.x * blockDim.x + threadIdx.x) >> 6);
    int lane = threadIdx.x & 63;
    int li   = lane & 31;
    int sub  = lane >> 5;
    if (pair >= (n >> 1)) return;
    int row = pair * 2 + sub;

    int idxv = (li < K)
        ? __builtin_nontemporal_load(idx_mat + (size_t)row * K + li) : 0;

    unsigned int t[K];
    #pragma unroll
    for (int k = 0; k < K; ++k) {
        int col = __shfl(idxv, sub * 32 + k);
        t[k] = tabQ[(size_t)col * FS + li];
    }

    float a0 = 0.f, a1 = 0.f, a2 = 0.f, a3 = 0.f;
    #pragma unroll
    for (int k = 0; k < K; ++k) {
        float sc = __uint_as_float((unsigned int)__shfl((int)t[k], sub * 32 + 25));
        unsigned int u = t[k];
        a0 += (float)((signed char)(u       & 0xFF)) * sc;
        a1 += (float)((signed char)((u >> 8) & 0xFF)) * sc;
        a2 += (float)((signed char)((u >> 16) & 0xFF)) * sc;
        a3 += (float)((int)u >> 24) * sc;
    }

    float o0 = 0.f, o1 = 0.f, o2 = 0.f, o3 = 0.f, lmax = 0.f;
    if (li < 25) {
        const float* bp = base + (size_t)row * D + li * 4;
        o0 = a0 + __builtin_nontemporal_load(bp + 0);
        o1 = a1 + __builtin_nontemporal_load(bp + 1);
        o2 = a2 + __builtin_nontemporal_load(bp + 2);
        o3 = a3 + __builtin_nontemporal_load(bp + 3);
        float* np = node + (size_t)row * D + li * 4;
        __builtin_nontemporal_store(o0, np + 0);
        __builtin_nontemporal_store(o1, np + 1);
        __builtin_nontemporal_store(o2, np + 2);
        __builtin_nontemporal_store(o3, np + 3);
        lmax = fmaxf(fmaxf(fabsf(o0), fabsf(o1)),
                     fmaxf(fabsf(o2), fabsf(o3)));
    }
    // half-wave rowmax reduce + int8 quantize (same layout as prep tables)
    #pragma unroll
    for (int off = 16; off >= 1; off >>= 1)
        lmax = fmaxf(lmax, __shfl_xor(lmax, off));
    float inv = (lmax > 0.f) ? (127.0f / lmax) : 0.f;

    unsigned int oq = 0;
    if (li < 25) {
        int q0 = (int)rintf(o0 * inv);
        int q1 = (int)rintf(o1 * inv);
        int q2 = (int)rintf(o2 * inv);
        int q3 = (int)rintf(o3 * inv);
        oq = ((unsigned int)(unsigned char)(signed char)q0)
           | ((unsigned int)(unsigned char)(signed char)q1 << 8)
           | ((unsigned int)(unsigned char)(signed char)q2 << 16)
           | ((unsigned int)(unsigned char)(signed char)q3 << 24);
    } else if (li == 25) {
        oq = __float_as_uint(lmax * (1.0f / 127.0f));
    }
    nodeQ[(size_t)row * FS + li] = oq;   // 32 lanes x 4 B = full line
}

// ---------------------------------------------------------------------------
// Per-user aggregate over the int8 node shadow. TWO entries per wave: each
// 32-lane half gathers one full 128 B line; halves combined via shfl_xor(32).
//   user[u,:] = user_emb[u,:] + sum vals*nodeQ[cols,:]
// ---------------------------------------------------------------------------
__global__ __launch_bounds__(256) void user_agg_q8_kernel(
    const int* __restrict__ counts, const unsigned int* __restrict__ bpack,
    const unsigned int* __restrict__ nodeQ,
    const float* __restrict__ user_emb, float* __restrict__ user)
{
    int u    = (int)((blockIdx.x * blockDim.x + threadIdx.x) >> 6);
    int lane = threadIdx.x & 63;
    int li   = lane & 31;
    int sub  = lane >> 5;
    if (u >= N_USER) return;

    int c = counts[u];
    if (c > CAP) c = CAP;

    int colv = 0; float valv = 0.f;
    if (lane < c) {
        unsigned int pk = __builtin_nontemporal_load(bpack + (size_t)u * CAP + lane);
        colv = (int)(pk & 0x1FFFFu);
        valv = (float)(pk >> 17) * (1.0f / 32767.0f);
    }
    int clampi = (c > 0) ? (c - 1) : 0;
    int pairs  = (c + 1) >> 1;

    float a0 = 0.f, a1 = 0.f, a2 = 0.f, a3 = 0.f;
    for (int p0 = 0; p0 < pairs; p0 += 4) {
        unsigned int t[4]; float v[4];
        #pragma unroll
        for (int e = 0; e < 4; ++e) {
            int pe    = 2 * (p0 + e) + sub;           // entry for this half
            bool valid = pe < c;
            int es    = valid ? pe : clampi;          // dup loads -> cache hits
            int   col = __shfl(colv, es);
            float vv  = __shfl(valv, es);
            v[e] = valid ? vv : 0.f;
            t[e] = nodeQ[(size_t)col * FS + li];
        }
        #pragma unroll
        for (int e = 0; e < 4; ++e) {
            float sc = __uint_as_float(
                (unsigned int)__shfl((int)t[e], sub * 32 + 25)) * v[e];
            unsigned int w = t[e];
            a0 += (float)((signed char)(w       & 0xFF)) * sc;
            a1 += (float)((signed char)((w >> 8) & 0xFF)) * sc;
            a2 += (float)((signed char)((w >> 16) & 0xFF)) * sc;
            a3 += (float)((int)w >> 24) * sc;
        }
    }
    // combine even/odd entry halves
    a0 += __shfl_xor(a0, 32);
    a1 += __shfl_xor(a1, 32);
    a2 += __shfl_xor(a2, 32);
    a3 += __shfl_xor(a3, 32);

    if (sub == 0 && li < 25) {
        const float* up = user_emb + (size_t)u * D + li * 4;
        float u0 = __builtin_nontemporal_load(up + 0);
        float u1 = __builtin_nontemporal_load(up + 1);
        float u2 = __builtin_nontemporal_load(up + 2);
        float u3 = __builtin_nontemporal_load(up + 3);
        float* op = user + (size_t)u * D + li * 4;
        __builtin_nontemporal_store(a0 + u0, op + 0);
        __builtin_nontemporal_store(a1 + u1, op + 1);
        __builtin_nontemporal_store(a2 + u2, op + 2);
        __builtin_nontemporal_store(a3 + u3, op + 3);
    }
}

// ---------------------------------------------------------------------------
// Overflow drain: entries hist pushed past CAP (none expected). f32 node.
// ---------------------------------------------------------------------------
__global__ __launch_bounds__(256) void drain_kernel(
    const int* __restrict__ list, const int* __restrict__ listcnt,
    const int* __restrict__ rows, const int* __restrict__ cols,
    const float* __restrict__ vals, const float* __restrict__ node,
    float* __restrict__ user)
{
    int nw   = (int)((gridDim.x * blockDim.x) >> 6);
    int wid  = (int)((blockIdx.x * blockDim.x + threadIdx.x) >> 6);
    int lane = threadIdx.x & 63;
    int cnt  = *listcnt;
    if (cnt > NNZ) cnt = NNZ;
    for (int s = wid; s < cnt; s += nw) {
        int j = list[s];
        int   r = rows[j];
        int   c = cols[j];
        float v = vals[j];
        const float* src = node + (size_t)c * D;
        float*       dst = user + (size_t)r * D;
        unsafeAtomicAdd(&dst[lane], v * src[lane]);
        int l2 = lane + 64;
        if (l2 < D) unsafeAtomicAdd(&dst[l2], v * src[l2]);
    }
}

// ---------------------------------------------------------------------------
// Fallback tiers (f32; only if workspace too small — never hit in practice)
// ---------------------------------------------------------------------------
__global__ __launch_bounds__(256) void zero2_kernel(
    int* __restrict__ counts, int* __restrict__ listcnt, int n)
{
    int i = (int)(blockIdx.x * blockDim.x + threadIdx.x);
    if (i < n) counts[i] = 0;
    else if (i == n) *listcnt = 0;
}

__global__ __launch_bounds__(256) void sumagg_f32_kernel(
    const float* __restrict__ table, const int* __restrict__ idx_mat,
    const float* __restrict__ base, float* __restrict__ out, int n)
{
    int wave = (int)((blockIdx.x * blockDim.x + threadIdx.x) >> 6);
    int lane = threadIdx.x & 63;
    if (wave >= n) return;
    int idxv = (lane < K) ? idx_mat[(size_t)wave * K + lane] : 0;
    float acc0 = 0.f, acc1 = 0.f;
    int l2 = lane + 64;
    #pragma unroll
    for (int k = 0; k < K; ++k) {
        int ei = __shfl(idxv, k);
        const float* r = table + (size_t)ei * D;
        acc0 += r[lane];
        if (l2 < D) acc1 += r[l2];
    }
    const float* b = base + (size_t)wave * D;
    float*       o = out  + (size_t)wave * D;
    o[lane] = acc0 + b[lane];
    if (l2 < D) o[l2] = acc1 + b[l2];
}

__global__ __launch_bounds__(256) void user_agg_f32_kernel(
    const int* __restrict__ counts, const unsigned int* __restrict__ bpack,
    const float* __restrict__ node,
    const float* __restrict__ user_emb, float* __restrict__ user)
{
    int u    = (int)((blockIdx.x * blockDim.x + threadIdx.x) >> 6);
    int lane = threadIdx.x & 63;
    if (u >= N_USER) return;
    int c = counts[u];
    if (c > CAP) c = CAP;
    int colv = 0; float valv = 0.f;
    if (lane < c) {
        unsigned int pk = bpack[(size_t)u * CAP + lane];
        colv = (int)(pk & 0x1FFFFu);
        valv = (float)(pk >> 17) * (1.0f / 32767.0f);
    }
    float a0 = 0.f, a1 = 0.f;
    int l2 = lane + 64;
    for (int e = 0; e < c; ++e) {
        int   col = __shfl(colv, e);
        float v   = __shfl(valv, e);
        const float* r = node + (size_t)col * D;
        a0 += v * r[lane];
        if (l2 < D) a1 += v * r[l2];
    }
    const float* ue = user_emb + (size_t)u * D;
    float*       o  = user     + (size_t)u * D;
    o[lane] = a0 + ue[lane];
    if (l2 < D) o[l2] = a1 + ue[l2];
}

__global__ __launch_bounds__(256) void copy_kernel(
    const float4* __restrict__ src, float4* __restrict__ dst, int n4)
{
    int i = (int)(blockIdx.x * blockDim.x + threadIdx.x);
    if (i < n4) dst[i] = src[i];
}

__global__ __launch_bounds__(256) void scatter_kernel(
    const float* __restrict__ vals, const int* __restrict__ rows,
    const int* __restrict__ cols, const float* __restrict__ node,
    float* __restrict__ user, int nnz)
{
    int j    = (int)((blockIdx.x * blockDim.x + threadIdx.x) >> 6);
    int lane = threadIdx.x & 63;
    if (j >= nnz) return;
    int   r = rows[j];
    int   c = cols[j];
    float v = vals[j];
    const float* src = node + (size_t)c * D;
    float*       dst = user + (size_t)r * D;
    unsafeAtomicAdd(&dst[lane], v * src[lane]);
    int l2 = lane + 64;
    if (l2 < D) unsafeAtomicAdd(&dst[l2], v * src[l2]);
}

// ---------------------------------------------------------------------------
extern "C" void kernel_launch(void* const* d_in, const int* in_sizes, int n_in,
                              void* d_out, int out_size, void* d_ws, size_t ws_size,
                              hipStream_t stream)
{
    const float* user_emb = (const float*)d_in[0];
    const float* all_emb  = (const float*)d_in[1];
    const float* ent_emb  = (const float*)d_in[2];
    // d_in[3..7]: relation_emb, W_news, b_news, W_ent, b_ent — dead inputs
    // (softmax over a size-1 axis is identically 1.0 in the reference).
    const float* vals     = (const float*)d_in[8];
    const int*   news_ent = (const int*)d_in[9];
    const int*   ngh_ent  = (const int*)d_in[11];
    const int*   irows    = (const int*)d_in[13];
    const int*   icols    = (const int*)d_in[14];

    float* node = (float*)d_out;                         // 80000 x 100
    float* user = (float*)d_out + (size_t)N_NODE * D;    // 50000 x 100

    // workspace layout (tier A)
    int*   counts  = (int*)d_ws;                              // N_USER
    int*   list    = counts + N_USER;                         // NNZ
    int*   listcnt = list + NNZ;                              // 1 (+63 pad)
    unsigned int* bpack = (unsigned int*)(listcnt + 64);      // N_USER*CAP
    unsigned int* entQ  = bpack + (size_t)N_USER * CAP;       // N_ENTITY*FS
    unsigned int* allQ  = entQ + (size_t)N_ENTITY * FS;       // N_ENTITY*FS
    unsigned int* nodeQ = allQ + (size_t)N_ENTITY * FS;       // N_NODE*FS

    size_t need_bucket = ((size_t)N_USER + NNZ + 64 + (size_t)N_USER * CAP) * 4ull;
    size_t need_full   = need_bucket
                       + (2ull * N_ENTITY + N_NODE) * FS * 4ull;

    if (ws_size >= need_full) {
        // ---- tier A: int8 single-line gathers end-to-end ----
        int prep_n = PREP_ROWT + N_USER + 1;
        prep_kernel<<<(prep_n + 255) / 256, 256, 0, stream>>>(
            ent_emb, all_emb, entQ, allQ, counts, listcnt);
        hist_fill_kernel<<<(NNZ + 255) / 256, 256, 0, stream>>>(
            irows, icols, vals, counts, bpack, list, listcnt, NNZ);

        // news: gathers q8(entity_emb); dual-row waves -> n/2 waves
        sumagg_q8_kernel<<<(N_NEWS / 2 + 3) / 4, 256, 0, stream>>>(
            entQ, news_ent, all_emb, node, nodeQ, N_NEWS);
        // entity: gathers q8(all_embedding)
        sumagg_q8_kernel<<<(N_ENTITY / 2 + 3) / 4, 256, 0, stream>>>(
            allQ, ngh_ent, all_emb, node + (size_t)N_NEWS * D,
            nodeQ + (size_t)N_NEWS * FS, N_ENTITY);

        user_agg_q8_kernel<<<(N_USER + 3) / 4, 256, 0, stream>>>(
            counts, bpack, nodeQ, user_emb, user);
        drain_kernel<<<64, 256, 0, stream>>>(
            list, listcnt, irows, icols, vals, node, user);
    } else if (ws_size >= need_bucket) {
        // ---- tier B: f32 bucket-gather ----
        sumagg_f32_kernel<<<(N_NEWS + 3) / 4, 256, 0, stream>>>(
            ent_emb, news_ent, all_emb, node, N_NEWS);
        sumagg_f32_kernel<<<(N_ENTITY + 3) / 4, 256, 0, stream>>>(
            all_emb, ngh_ent, all_emb, node + (size_t)N_NEWS * D, N_ENTITY);
        zero2_kernel<<<(N_USER + 256) / 256, 256, 0, stream>>>(
            counts, listcnt, N_USER);
        hist_fill_kernel<<<(NNZ + 255) / 256, 256, 0, stream>>>(
            irows, icols, vals, counts, bpack, list, listcnt, NNZ);
        user_agg_f32_kernel<<<(N_USER + 3) / 4, 256, 0, stream>>>(
            counts, bpack, node, user_emb, user);
        drain_kernel<<<64, 256, 0, stream>>>(
            list, listcnt, irows, icols, vals, node, user);
    } else {
        // ---- tier C: atomic scatter ----
        sumagg_f32_kernel<<<(N_NEWS + 3) / 4, 256, 0, stream>>>(
            ent_emb, news_ent, all_emb, node, N_NEWS);
        sumagg_f32_kernel<<<(N_ENTITY + 3) / 4, 256, 0, stream>>>(
            all_emb, ngh_ent, all_emb, node + (size_t)N_NEWS * D, N_ENTITY);
        int n4 = N_USER * D / 4;
        copy_kernel<<<(n4 + 255) / 256, 256, 0, stream>>>(
            (const float4*)user_emb, (float4*)user, n4);
        scatter_kernel<<<(NNZ + 3) / 4, 256, 0, stream>>>(
            vals, irows, icols, node, user, NNZ);
    }
}